// Round 11
// baseline (603.251 us; speedup 1.0000x reference)
//
#include <hip/hip_runtime.h>
#include <math.h>

#define H 256
#define G3 768        // 3*H
#define BB 512
#define AA 4
#define EE 10
#define RP (BB*AA*EE) // 20480 physical rows
#define RA (BB*AA)    // 2048 action rows
#define TT 10
#define NMV 2
#define STEPSC 0.05f
#define DST 260       // act LDS row stride (floats)
#define A1B 128       // act1: pool + action GRU
#define A2B 256       // act2: fc_a (col-split x2)
#define A3B 128       // act3: m1 + m2
#define COMB 1280     // combined fc+gru: 160 row-tiles (128 rows) x 8 col-groups

typedef __attribute__((ext_vector_type(8))) short short8;
typedef __attribute__((ext_vector_type(8))) _Float16 half8;
typedef __attribute__((ext_vector_type(4))) _Float16 half4;
typedef __attribute__((ext_vector_type(4))) float f32x4;

#if defined(__has_builtin)
#  if __has_builtin(__builtin_amdgcn_global_load_lds)
#    define HAS_GLL 1
#  endif
#endif

__device__ __forceinline__ float sigmoid_(float x){ return 1.f/(1.f + __expf(-x)); }
__device__ __forceinline__ float tanh_(float x){
    float ax = fabsf(x);
    float e  = __expf(-2.f*ax);
    float t  = (1.f - e)/(1.f + e);
    return copysignf(t, x);
}
__device__ __forceinline__ float elu_(float x){ return x > 0.f ? x : (__expf(x) - 1.f); }

// Operand-SWAPPED MFMA: weights as A, activations as B.  D^T layout gives
// each thread 4 CONSECUTIVE output columns of one sample -> 8B coalesced
// epilogue loads/stores.  Same dot products: bit-identical numerics.
#define MFMA16(A,B,C) __builtin_amdgcn_mfma_f32_16x16x32_f16(A,B,C,0,0,0)

__device__ __forceinline__ void cp16(const void* g, void* l) {
#ifdef HAS_GLL
    __builtin_amdgcn_global_load_lds(
        (const __attribute__((address_space(1))) unsigned int*)g,
        (__attribute__((address_space(3))) unsigned int*)l, 16, 0, 0);
#else
    *(short8*)l = *(const short8*)g;
#endif
}

// ---------------------------------------------------------------------------
// fp32 weight [Nout][ldsrc] -> fp16 in MFMA fragment order (A or B — symmetric).
// ---------------------------------------------------------------------------
__global__ void k_splitw(const float* __restrict__ src, _Float16* __restrict__ dst,
                         int n, int ldsrc)
{
    int i = blockIdx.x*256 + threadIdx.x;
    if (i < n) {
        int j  = i & 7;
        int l  = (i >> 3) & 63;
        int kc = (i >> 9) & 7;
        int c  = i >> 12;
        int row = c*16 + (l & 15);
        int k   = kc*32 + (l >> 4)*8 + j;
        dst[i] = (_Float16)src[(size_t)row*ldsrc + k];
    }
}

// gia[ra][k] = b_ih_a[k] (+ b_hh_a[k] for r,z gates) + goals·W_ih_a[k][256:259]
__global__ void k_gia_goal(const float* __restrict__ goals,
                           const float* __restrict__ Wiha,
                           const float* __restrict__ biha,
                           const float* __restrict__ bhha,
                           _Float16* __restrict__ out)
{
    int idx = blockIdx.x*256 + threadIdx.x;
    int ra = idx / G3, k = idx % G3;
    float g0 = goals[ra*3+0], g1 = goals[ra*3+1], g2 = goals[ra*3+2];
    const float* w = Wiha + (size_t)k*259 + 256;
    float base = biha[k] + (k < 512 ? bhha[k] : 0.f);
    out[idx] = (_Float16)(base + g0*w[0] + g1*w[1] + g2*w[2]);
}

// fp32 -> fp16 convert (state init)
__global__ void k_cvt(const float* __restrict__ src, _Float16* __restrict__ dst, int n)
{
    int i = blockIdx.x*256 + threadIdx.x;
    if (i < n) dst[i] = (_Float16)src[i];
}

// ---------------------------------------------------------------------------
// xext[row][32] = [obs0, obs1, phys0, phys1, phys2, 1, 0...]  (fp16)
// ---------------------------------------------------------------------------
__global__ void k_xext(const float* __restrict__ obs, const float* __restrict__ phys,
                       _Float16* __restrict__ dst)
{
    int i = blockIdx.x*256 + threadIdx.x;  // RP*32
    int row = i >> 5, j = i & 31;
    float v = 0.f;
    if (j < 2) v = obs[(size_t)row*2 + j];
    else if (j < 5) {
        int bb = row / (AA*EE), e = row % EE;
        v = phys[(size_t)(bb*EE + e)*3 + (j - 2)];
    } else if (j == 5) v = 1.f;
    dst[i] = (_Float16)v;
}

// ---------------------------------------------------------------------------
// wXih: K=32 extension slab fragment (x-dot + bias fold).
// ---------------------------------------------------------------------------
__global__ void k_wxih(const float* __restrict__ Wih, const float* __restrict__ bih,
                       const float* __restrict__ bhh, _Float16* __restrict__ dst)
{
    int i = blockIdx.x*256 + threadIdx.x;  // 48*512 = 24576
    int j = i & 7, l = (i >> 3) & 63, chunk = i >> 9;
    int g = chunk >> 4, cs = chunk & 15;
    int ocol = g*256 + cs*16 + (l & 15);
    int k32 = (l >> 4)*8 + j;
    float v = 0.f;
    if (k32 < 5) v = Wih[(size_t)ocol*5 + k32];
    else if (k32 == 5) v = bih[ocol] + (g < 2 ? bhh[ocol] : 0.f);
    dst[i] = (_Float16)v;
}

// ---------------------------------------------------------------------------
// FUSED STEP KERNEL — 5-stage pipeline + R6 MFMA bias/x-fold + R7 swapped
// (coalesced) epilogues + R10 single-barrier prefetch.
// Round-11: COMB LDS 64KB -> 48KB.  Both gru slices stay LDS-staged (R9:
// gru direct-global is fatal, 4x L2 amplification on 60MB); fc weights (16KB,
// 16 MFMAs) read DIRECT from global with R9's verified indexing.  48KB ->
// 3 blocks/CU (was 2) = +50% resident waves for latency hiding.
// ---------------------------------------------------------------------------
__global__ __launch_bounds__(256, 2)
void k_step(int gru_t, int fc_t, int a1_t, int a2_t, int a3_t,
            _Float16* __restrict__ hp0, _Float16* __restrict__ hp1,
            _Float16* __restrict__ proc0, _Float16* __restrict__ proc1,
            _Float16* __restrict__ ha0, _Float16* __restrict__ ha1,
            _Float16* __restrict__ pca0, _Float16* __restrict__ pca1,
            const _Float16* __restrict__ wWhh, const _Float16* __restrict__ wWfc,
            const _Float16* __restrict__ wWhha, const _Float16* __restrict__ wWiha,
            const _Float16* __restrict__ wWfca, const _Float16* __restrict__ wWm1,
            const _Float16* __restrict__ gia,
            const _Float16* __restrict__ xext, const _Float16* __restrict__ wXih,
            const float* __restrict__ bhh, const float* __restrict__ bfcp,
            const float* __restrict__ bhha, const float* __restrict__ bfca,
            const float* __restrict__ bm1,
            const float* __restrict__ Wm2, const float* __restrict__ bm2,
            float* __restrict__ out)
{
    __shared__ char smem[49152];   // COMB: Bw0|Bw1 = 24K|24K.  Acts: D (16.6K).
    int b = blockIdx.x;
    const int tid = threadIdx.x;
    const int wv = tid >> 6, lane = tid & 63;
    const int quad = lane >> 4, l16 = lane & 15;

    // ===================== ACT1: pool + action GRU =====================
    if (b < A1B) {
        if (a1_t < 0) return;
        float* D = (float*)smem;
        const _Float16* proc = (a1_t & 1) ? proc1 : proc0;
        const _Float16* hain = (a1_t & 1) ? ha1 : ha0;
        _Float16*      haout = (a1_t & 1) ? ha0 : ha1;
        const int ra0 = b*16;

        // pool: feat = max_e proc (half8-vectorized)
        for (int i = tid; i < 16*32; i += 256) {
            int r = i >> 5, cg = (i & 31)*8;
            const _Float16* p = proc + ((size_t)(ra0 + r)*EE)*H + cg;
            half8 v = *(const half8*)p;
            float m[8];
            #pragma unroll
            for (int j = 0; j < 8; j++) m[j] = (float)v[j];
            #pragma unroll
            for (int e = 1; e < EE; e++) {
                half8 u = *(const half8*)(p + (size_t)e*H);
                #pragma unroll
                for (int j = 0; j < 8; j++) m[j] = fmaxf(m[j], (float)u[j]);
            }
            #pragma unroll
            for (int j = 0; j < 8; j++) D[r*DST + cg + j] = m[j];
        }
        __syncthreads();

        half8 Fh[8], Hh[8];
        #pragma unroll
        for (int kc = 0; kc < 8; kc++) {
            const float* fp = &D[l16*DST + quad*8 + kc*32];
            #pragma unroll
            for (int j = 0; j < 8; j++) Fh[kc][j] = (_Float16)fp[j];
            Hh[kc] = *(const half8*)(hain + (size_t)(ra0 + l16)*H + quad*8 + kc*32);
        }

        const int smp = ra0 + l16;
        const _Float16* gp = gia + (size_t)smp*G3;
        #pragma unroll
        for (int p = 0; p < 2; p++) {
            f32x4 gh[3][2], gx[3][2];
            #pragma unroll
            for (int g = 0; g < 3; g++)
                #pragma unroll
                for (int ch = 0; ch < 2; ch++) {
                    gh[g][ch] = (f32x4){0.f,0.f,0.f,0.f};
                    gx[g][ch] = (f32x4){0.f,0.f,0.f,0.f};
                }
            #pragma unroll
            for (int kc = 0; kc < 8; kc++)
                #pragma unroll
                for (int ch = 0; ch < 2; ch++)
                    #pragma unroll
                    for (int g = 0; g < 3; g++) {
                        const size_t cg = (size_t)(g*16 + wv*4 + p*2 + ch);
                        half8 bh = *(const half8*)(wWhha + (cg*8+kc)*512 + lane*8);
                        half8 bx = *(const half8*)(wWiha + (cg*8+kc)*512 + lane*8);
                        gh[g][ch] = MFMA16(bh, Hh[kc], gh[g][ch]);   // swapped
                        gx[g][ch] = MFMA16(bx, Fh[kc], gx[g][ch]);   // swapped
                    }
            #pragma unroll
            for (int ch = 0; ch < 2; ch++) {
                const int c0 = (wv*4 + p*2 + ch)*16 + quad*4;        // 4 consecutive cols
                half4 gr4 = *(const half4*)(gp + c0);
                half4 gz4 = *(const half4*)(gp + 256 + c0);
                half4 gn4 = *(const half4*)(gp + 512 + c0);
                f32x4 bn4 = *(const f32x4*)&bhha[512 + c0];
                half4 hp4 = *(const half4*)(hain + (size_t)smp*H + c0);
                half4 ho;
                #pragma unroll
                for (int r = 0; r < 4; r++) {
                    float rg = sigmoid_((float)gr4[r] + gx[0][ch][r] + gh[0][ch][r]);
                    float z  = sigmoid_((float)gz4[r] + gx[1][ch][r] + gh[1][ch][r]);
                    float n  = tanh_((float)gn4[r] + gx[2][ch][r] + rg*(gh[2][ch][r] + bn4[r]));
                    ho[r] = (_Float16)((1.f - z)*n + z*(float)hp4[r]);
                }
                *(half4*)(haout + (size_t)smp*H + c0) = ho;
            }
        }
        return;
    }
    b -= A1B;

    // ===================== ACT2: fc_a (col-split) =====================
    if (b < A2B) {
        if (a2_t < 0) return;
        const _Float16* hnew = (a2_t & 1) ? ha0 : ha1;   // ha[(t+1)&1]
        _Float16*       pca  = (a2_t & 1) ? pca1 : pca0;
        const int ra0 = (b >> 1)*16;
        const int half = b & 1;

        half8 Hh[8];
        #pragma unroll
        for (int kc = 0; kc < 8; kc++)
            Hh[kc] = *(const half8*)(hnew + (size_t)(ra0 + l16)*H + quad*8 + kc*32);

        f32x4 ac[2];
        ac[0] = (f32x4){0.f,0.f,0.f,0.f};
        ac[1] = (f32x4){0.f,0.f,0.f,0.f};
        #pragma unroll
        for (int kc = 0; kc < 8; kc++)
            #pragma unroll
            for (int ch = 0; ch < 2; ch++) {
                const size_t cidx = (size_t)(half*8 + wv*2 + ch);
                half8 w = *(const half8*)(wWfca + (cidx*8+kc)*512 + lane*8);
                ac[ch] = MFMA16(w, Hh[kc], ac[ch]);                  // swapped
            }
        const int smp = ra0 + l16;
        #pragma unroll
        for (int ch = 0; ch < 2; ch++) {
            const int c0 = (half*8 + wv*2 + ch)*16 + quad*4;
            f32x4 bs4 = *(const f32x4*)&bfca[c0];
            half4 po;
            #pragma unroll
            for (int r = 0; r < 4; r++)
                po[r] = (_Float16)elu_(ac[ch][r] + bs4[r]);
            *(half4*)(pca + (size_t)smp*H + c0) = po;
        }
        return;
    }
    b -= A2B;

    // ===================== ACT3: m1 + m2 =====================
    if (b < A3B) {
        if (a3_t < 0) return;
        float* D = (float*)smem;
        const _Float16* pca = (a3_t & 1) ? pca1 : pca0;
        const int ra0 = b*16;

        half8 Ph[8];
        #pragma unroll
        for (int kc = 0; kc < 8; kc++)
            Ph[kc] = *(const half8*)(pca + (size_t)(ra0 + l16)*H + quad*8 + kc*32);

        f32x4 ac[4];
        #pragma unroll
        for (int ch = 0; ch < 4; ch++) ac[ch] = (f32x4){0.f,0.f,0.f,0.f};
        #pragma unroll
        for (int kc = 0; kc < 8; kc++)
            #pragma unroll
            for (int ch = 0; ch < 4; ch++) {
                half8 w = *(const half8*)(wWm1 + ((size_t)(wv*4+ch)*8+kc)*512 + lane*8);
                ac[ch] = MFMA16(w, Ph[kc], ac[ch]);                  // swapped
            }
        #pragma unroll
        for (int ch = 0; ch < 4; ch++) {
            const int c0 = (wv*4 + ch)*16 + quad*4;
            f32x4 bs4 = *(const f32x4*)&bm1[c0];
            f32x4 dv;
            #pragma unroll
            for (int r = 0; r < 4; r++) dv[r] = elu_(ac[ch][r] + bs4[r]);
            *(f32x4*)&D[l16*DST + c0] = dv;
        }
        __syncthreads();

        if (tid < 32) {
            int r = tid >> 1, v = tid & 1;
            const float* w = Wm2 + (size_t)v*H;
            float s = bm2[v];
            #pragma unroll 4
            for (int i = 0; i < H/4; i++) {
                float4 a = *(const float4*)&D[r*DST + i*4];
                float4 c = *(const float4*)&w[i*4];
                s = fmaf(a.x,c.x,s); s = fmaf(a.y,c.y,s);
                s = fmaf(a.z,c.z,s); s = fmaf(a.w,c.w,s);
            }
            out[((size_t)a3_t*RA + ra0 + r)*NMV + v] = tanh_(s)*STEPSC;
        }
        return;
    }
    b -= A3B;

    // ==== COMBINED fc(fc_t)+gru(gru_t): single-barrier, 48KB LDS ====
    {
        const bool do_gru = (gru_t >= 0);
        const bool do_fc  = (fc_t >= 0);
        if (!do_gru && !do_fc) return;
        _Float16* Bw0 = (_Float16*)smem;            // gru slice 0 (24576 B)
        _Float16* Bw1 = (_Float16*)(smem + 24576);  // gru slice 1 (24576 B)
        const int par = do_gru ? (gru_t & 1) : ((fc_t + 1) & 1);
        const _Float16* hin  = par ? hp1 : hp0;
        _Float16*       hout = par ? hp0 : hp1;            // gru output
        _Float16*       pout = (fc_t & 1) ? proc1 : proc0; // fc output
        const int xm = b % 160, ys = b / 160;              // ys in 0..7
        const int mt0 = xm*128 + wv*16;                    // tile 0 rows
        const int mt1 = mt0 + 64;                          // tile 1 rows

        // Stage both gru slices at once (latency overlaps A-frag loads)
        if (do_gru) {
            #pragma unroll
            for (int k = 0; k < 6; k++) {
                int i = tid + 256*k;
                int g = i >> 9;
                cp16(wWhh + (size_t)(g*16 + ys*2)*4096 + (i & 511)*8, &Bw0[(size_t)i*8]);
            }
            #pragma unroll
            for (int k = 0; k < 6; k++) {
                int i = tid + 256*k;
                int g = i >> 9;
                cp16(wWhh + (size_t)(g*16 + ys*2+1)*4096 + (i & 511)*8, &Bw1[(size_t)i*8]);
            }
        }

        // h fragments (B-operand), loaded ONCE, shared by gru slices AND fc
        half8 Ah[2][8];
        #pragma unroll
        for (int kc = 0; kc < 8; kc++) {
            Ah[0][kc] = *(const half8*)(hin + (size_t)(mt0 + l16)*H + quad*8 + kc*32);
            Ah[1][kc] = *(const half8*)(hin + (size_t)(mt1 + l16)*H + quad*8 + kc*32);
        }

        // fc first (independent of LDS) — its global weight loads overlap
        // the gru staging still in flight.
        if (do_fc) {
            const int cs2 = ys;                            // 0..7, 32 cols
            const _Float16* wf = wWfc + (size_t)cs2*8192 + (size_t)lane*8;
            f32x4 acc[2][2];
            #pragma unroll
            for (int mt = 0; mt < 2; mt++)
                #pragma unroll
                for (int ni = 0; ni < 2; ni++) acc[mt][ni] = (f32x4){0.f,0.f,0.f,0.f};
            #pragma unroll
            for (int kc = 0; kc < 8; kc++)
                #pragma unroll
                for (int ni = 0; ni < 2; ni++) {
                    half8 w = *(const half8*)(wf + ni*4096 + kc*512);
                    acc[0][ni] = MFMA16(w, Ah[0][kc], acc[0][ni]);   // swapped
                    acc[1][ni] = MFMA16(w, Ah[1][kc], acc[1][ni]);
                }
            #pragma unroll
            for (int ni = 0; ni < 2; ni++) {
                const int c0 = cs2*32 + ni*16 + quad*4;
                f32x4 bs4 = *(const f32x4*)&bfcp[c0];
                #pragma unroll
                for (int mt = 0; mt < 2; mt++) {
                    const int smp = (mt ? mt1 : mt0) + l16;
                    half4 po;
                    #pragma unroll
                    for (int r = 0; r < 4; r++)
                        po[r] = (_Float16)elu_(acc[mt][ni][r] + bs4[r]);
                    *(half4*)(pout + (size_t)smp*H + c0) = po;
                }
            }
        }

        if (do_gru) {
            __syncthreads();           // ONE barrier: gru staging landed

            half8 Xh[2];
            Xh[0] = *(const half8*)(xext + (size_t)(mt0 + l16)*32 + quad*8);
            Xh[1] = *(const half8*)(xext + (size_t)(mt1 + l16)*32 + quad*8);

            #pragma unroll
            for (int s = 0; s < 2; s++) {
                const int cs = ys*2 + s;                   // 0..15
                const _Float16* Bw = s ? Bw1 : Bw0;

                f32x4 acc[2][3], accHN[2];
                #pragma unroll
                for (int mt = 0; mt < 2; mt++) {
                    #pragma unroll
                    for (int g = 0; g < 3; g++) acc[mt][g] = (f32x4){0.f,0.f,0.f,0.f};
                    accHN[mt] = (f32x4){0.f,0.f,0.f,0.f};
                }
                #pragma unroll
                for (int kc = 0; kc < 8; kc++) {
                    #pragma unroll
                    for (int g = 0; g < 2; g++) {
                        half8 w = *(const half8*)&Bw[(g*8 + kc)*512 + lane*8];
                        acc[0][g] = MFMA16(w, Ah[0][kc], acc[0][g]); // swapped
                        acc[1][g] = MFMA16(w, Ah[1][kc], acc[1][g]);
                    }
                    half8 wn = *(const half8*)&Bw[(2*8 + kc)*512 + lane*8];
                    accHN[0] = MFMA16(wn, Ah[0][kc], accHN[0]);
                    accHN[1] = MFMA16(wn, Ah[1][kc], accHN[1]);
                }
                #pragma unroll
                for (int g = 0; g < 3; g++) {
                    half8 xw = *(const half8*)(wXih + (size_t)(g*16+cs)*512 + lane*8);
                    acc[0][g] = MFMA16(xw, Xh[0], acc[0][g]);        // swapped
                    acc[1][g] = MFMA16(xw, Xh[1], acc[1][g]);
                }

                const int c0 = cs*16 + quad*4;             // 4 consecutive cols
                f32x4 bn4 = *(const f32x4*)&bhh[512 + c0];
                #pragma unroll
                for (int mt = 0; mt < 2; mt++) {
                    const int smp = (mt ? mt1 : mt0) + l16;
                    half4 hp4 = *(const half4*)(hin + (size_t)smp*H + c0);
                    half4 ho;
                    #pragma unroll
                    for (int r = 0; r < 4; r++) {
                        float rg = sigmoid_(acc[mt][0][r]);
                        float z  = sigmoid_(acc[mt][1][r]);
                        float n  = tanh_(acc[mt][2][r] + rg*(accHN[mt][r] + bn4[r]));
                        ho[r] = (_Float16)((1.f - z)*n + z*(float)hp4[r]);
                    }
                    *(half4*)(hout + (size_t)smp*H + c0) = ho;
                }
            }
        }
    }
}

extern "C" void kernel_launch(void* const* d_in, const int* in_sizes, int n_in,
                              void* d_out, int out_size, void* d_ws, size_t ws_size,
                              hipStream_t stream)
{
    const float* obs  = (const float*)d_in[0];
    const float* phys = (const float*)d_in[1];
    const float* goals= (const float*)d_in[2];
    const float* memp = (const float*)d_in[3];
    const float* mema = (const float*)d_in[4];
    const float* Wihp = (const float*)d_in[5];
    const float* Whhp = (const float*)d_in[6];
    const float* bihp = (const float*)d_in[7];
    const float* bhhp = (const float*)d_in[8];
    const float* Wfcp = (const float*)d_in[9];
    const float* bfcp = (const float*)d_in[10];
    const float* Wiha = (const float*)d_in[11];
    const float* Whha = (const float*)d_in[12];
    const float* biha = (const float*)d_in[13];
    const float* bhha = (const float*)d_in[14];
    const float* Wfca = (const float*)d_in[15];
    const float* bfca = (const float*)d_in[16];
    const float* Wm1  = (const float*)d_in[17];
    const float* bm1  = (const float*)d_in[18];
    const float* Wm2  = (const float*)d_in[19];
    const float* bm2  = (const float*)d_in[20];
    float* out = (float*)d_out;
    (void)ws_size;

    char* base = (char*)d_ws;
    size_t off = 0;
    auto alloc = [&](size_t bytes) -> char* {
        char* p = base + off;
        off += (bytes + 255) & ~(size_t)255;
        return p;
    };
    _Float16* wp_whh = (_Float16*)alloc((size_t)G3*H*2);
    _Float16* wp_wfc = (_Float16*)alloc((size_t)H*H*2);
    _Float16* wa_whh = (_Float16*)alloc((size_t)G3*H*2);
    _Float16* wa_wih = (_Float16*)alloc((size_t)G3*H*2);
    _Float16* wa_wfc = (_Float16*)alloc((size_t)H*H*2);
    _Float16* wa_wm1 = (_Float16*)alloc((size_t)H*H*2);
    _Float16* gia    = (_Float16*)alloc((size_t)RA*G3*2);
    _Float16* hp0    = (_Float16*)alloc((size_t)RP*H*2);
    _Float16* hp1    = (_Float16*)alloc((size_t)RP*H*2);
    _Float16* proc0  = (_Float16*)alloc((size_t)RP*H*2);
    _Float16* proc1  = (_Float16*)alloc((size_t)RP*H*2);
    _Float16* ha0    = (_Float16*)alloc((size_t)RA*H*2);
    _Float16* ha1    = (_Float16*)alloc((size_t)RA*H*2);
    _Float16* pca0   = (_Float16*)alloc((size_t)RA*H*2);
    _Float16* pca1   = (_Float16*)alloc((size_t)RA*H*2);
    _Float16* xext   = (_Float16*)alloc((size_t)RP*32*2);   // 1.25 MB
    _Float16* wxih   = (_Float16*)alloc((size_t)48*512*2);  // 48 KB

    // --- pre-pass ---
    k_splitw<<<(G3*H+255)/256, 256, 0, stream>>>(Whhp, wp_whh, G3*H, H);
    k_splitw<<<(H*H+255)/256, 256, 0, stream>>>(Wfcp, wp_wfc, H*H, H);
    k_splitw<<<(G3*H+255)/256, 256, 0, stream>>>(Whha, wa_whh, G3*H, H);
    k_splitw<<<(G3*H+255)/256, 256, 0, stream>>>(Wiha, wa_wih, G3*H, 259);
    k_splitw<<<(H*H+255)/256, 256, 0, stream>>>(Wfca, wa_wfc, H*H, H);
    k_splitw<<<(H*H+255)/256, 256, 0, stream>>>(Wm1,  wa_wm1, H*H, H);
    k_gia_goal<<<RA*G3/256, 256, 0, stream>>>(goals, Wiha, biha, bhha, gia);
    k_cvt<<<((size_t)RP*H+255)/256, 256, 0, stream>>>(memp, hp0, RP*H);
    k_cvt<<<((size_t)RA*H+255)/256, 256, 0, stream>>>(mema, ha0, RA*H);
    k_xext<<<RP*32/256, 256, 0, stream>>>(obs, phys, xext);
    k_wxih<<<48*512/256, 256, 0, stream>>>(Wihp, bihp, bhhp, wxih);

    // --- 14 pipelined launches: L = {gru(L), fc(L-1), act1(L-2), act2(L-3), act3(L-4)} ---
    const int NB = A1B + A2B + A3B + COMB;
    for (int L = 0; L <= TT + 3; L++) {
        int gru_t = (L <= TT-1) ? L : -1;
        int fc_t  = (L-1 >= 0 && L-1 <= TT-1) ? L-1 : -1;
        int a1_t  = (L-2 >= 0 && L-2 <= TT-1) ? L-2 : -1;
        int a2_t  = (L-3 >= 0 && L-3 <= TT-1) ? L-3 : -1;
        int a3_t  = (L-4 >= 0 && L-4 <= TT-1) ? L-4 : -1;
        k_step<<<NB, 256, 0, stream>>>(gru_t, fc_t, a1_t, a2_t, a3_t,
                                       hp0, hp1, proc0, proc1, ha0, ha1, pca0, pca1,
                                       wp_whh, wp_wfc, wa_whh, wa_wih, wa_wfc, wa_wm1,
                                       gia, xext, wxih,
                                       bhhp, bfcp,
                                       bhha, bfca, bm1, Wm2, bm2, out);
    }
}

// Round 12
// 533.024 us; speedup vs baseline: 1.1318x; 1.1318x over previous
//
#include <hip/hip_runtime.h>
#include <math.h>

#define H 256
#define G3 768        // 3*H
#define BB 512
#define AA 4
#define EE 10
#define RP (BB*AA*EE) // 20480 physical rows
#define RA (BB*AA)    // 2048 action rows
#define TT 10
#define NMV 2
#define STEPSC 0.05f
#define DST 260       // act LDS row stride (floats)
#define A1B 128       // act1: pool + action GRU
#define A2B 256       // act2: fc_a (col-split x2)
#define A3B 128       // act3: m1 + m2
#define COMB 1280     // combined fc+gru: 160 row-tiles (128 rows) x 8 col-groups

typedef __attribute__((ext_vector_type(8))) short short8;
typedef __attribute__((ext_vector_type(8))) _Float16 half8;
typedef __attribute__((ext_vector_type(4))) _Float16 half4;
typedef __attribute__((ext_vector_type(4))) float f32x4;

#if defined(__has_builtin)
#  if __has_builtin(__builtin_amdgcn_global_load_lds)
#    define HAS_GLL 1
#  endif
#endif

__device__ __forceinline__ float sigmoid_(float x){ return 1.f/(1.f + __expf(-x)); }
__device__ __forceinline__ float tanh_(float x){
    float ax = fabsf(x);
    float e  = __expf(-2.f*ax);
    float t  = (1.f - e)/(1.f + e);
    return copysignf(t, x);
}
__device__ __forceinline__ float elu_(float x){ return x > 0.f ? x : (__expf(x) - 1.f); }

// Operand-SWAPPED MFMA: weights as A, activations as B.  D^T layout gives
// each thread 4 CONSECUTIVE output columns of one sample -> 8B coalesced
// epilogue loads/stores.  Same dot products: bit-identical numerics.
#define MFMA16(A,B,C) __builtin_amdgcn_mfma_f32_16x16x32_f16(A,B,C,0,0,0)

__device__ __forceinline__ void cp16(const void* g, void* l) {
#ifdef HAS_GLL
    __builtin_amdgcn_global_load_lds(
        (const __attribute__((address_space(1))) unsigned int*)g,
        (__attribute__((address_space(3))) unsigned int*)l, 16, 0, 0);
#else
    *(short8*)l = *(const short8*)g;
#endif
}

// ---------------------------------------------------------------------------
// fp32 weight [Nout][ldsrc] -> fp16 in MFMA fragment order (A or B — symmetric).
// ---------------------------------------------------------------------------
__global__ void k_splitw(const float* __restrict__ src, _Float16* __restrict__ dst,
                         int n, int ldsrc)
{
    int i = blockIdx.x*256 + threadIdx.x;
    if (i < n) {
        int j  = i & 7;
        int l  = (i >> 3) & 63;
        int kc = (i >> 9) & 7;
        int c  = i >> 12;
        int row = c*16 + (l & 15);
        int k   = kc*32 + (l >> 4)*8 + j;
        dst[i] = (_Float16)src[(size_t)row*ldsrc + k];
    }
}

// gia[ra][k] = b_ih_a[k] (+ b_hh_a[k] for r,z gates) + goals·W_ih_a[k][256:259]
__global__ void k_gia_goal(const float* __restrict__ goals,
                           const float* __restrict__ Wiha,
                           const float* __restrict__ biha,
                           const float* __restrict__ bhha,
                           _Float16* __restrict__ out)
{
    int idx = blockIdx.x*256 + threadIdx.x;
    int ra = idx / G3, k = idx % G3;
    float g0 = goals[ra*3+0], g1 = goals[ra*3+1], g2 = goals[ra*3+2];
    const float* w = Wiha + (size_t)k*259 + 256;
    float base = biha[k] + (k < 512 ? bhha[k] : 0.f);
    out[idx] = (_Float16)(base + g0*w[0] + g1*w[1] + g2*w[2]);
}

// fp32 -> fp16 convert (state init)
__global__ void k_cvt(const float* __restrict__ src, _Float16* __restrict__ dst, int n)
{
    int i = blockIdx.x*256 + threadIdx.x;
    if (i < n) dst[i] = (_Float16)src[i];
}

// ---------------------------------------------------------------------------
// xext[row][32] = [obs0, obs1, phys0, phys1, phys2, 1, 0...]  (fp16)
// ---------------------------------------------------------------------------
__global__ void k_xext(const float* __restrict__ obs, const float* __restrict__ phys,
                       _Float16* __restrict__ dst)
{
    int i = blockIdx.x*256 + threadIdx.x;  // RP*32
    int row = i >> 5, j = i & 31;
    float v = 0.f;
    if (j < 2) v = obs[(size_t)row*2 + j];
    else if (j < 5) {
        int bb = row / (AA*EE), e = row % EE;
        v = phys[(size_t)(bb*EE + e)*3 + (j - 2)];
    } else if (j == 5) v = 1.f;
    dst[i] = (_Float16)v;
}

// ---------------------------------------------------------------------------
// wXih: K=32 extension slab fragment (x-dot + bias fold).
// ---------------------------------------------------------------------------
__global__ void k_wxih(const float* __restrict__ Wih, const float* __restrict__ bih,
                       const float* __restrict__ bhh, _Float16* __restrict__ dst)
{
    int i = blockIdx.x*256 + threadIdx.x;  // 48*512 = 24576
    int j = i & 7, l = (i >> 3) & 63, chunk = i >> 9;
    int g = chunk >> 4, cs = chunk & 15;
    int ocol = g*256 + cs*16 + (l & 15);
    int k32 = (l >> 4)*8 + j;
    float v = 0.f;
    if (k32 < 5) v = Wih[(size_t)ocol*5 + k32];
    else if (k32 == 5) v = bih[ocol] + (g < 2 ? bhh[ocol] : 0.f);
    dst[i] = (_Float16)v;
}

// ---------------------------------------------------------------------------
// FUSED STEP KERNEL — 5-stage pipeline + R6 MFMA bias/x-fold + R7 swapped
// (coalesced) epilogues + R10 single-barrier prefetch COMB (measured best:
// k_step 42.8us, total 533us).  All three weight buffers (gru s0, gru s1, fc)
// staged at once into disjoint LDS regions (64 KB), ONE __syncthreads, then
// s0/s1/fc computed back-to-back with zero further syncs.
// ---------------------------------------------------------------------------
__global__ __launch_bounds__(256, 2)
void k_step(int gru_t, int fc_t, int a1_t, int a2_t, int a3_t,
            _Float16* __restrict__ hp0, _Float16* __restrict__ hp1,
            _Float16* __restrict__ proc0, _Float16* __restrict__ proc1,
            _Float16* __restrict__ ha0, _Float16* __restrict__ ha1,
            _Float16* __restrict__ pca0, _Float16* __restrict__ pca1,
            const _Float16* __restrict__ wWhh, const _Float16* __restrict__ wWfc,
            const _Float16* __restrict__ wWhha, const _Float16* __restrict__ wWiha,
            const _Float16* __restrict__ wWfca, const _Float16* __restrict__ wWm1,
            const _Float16* __restrict__ gia,
            const _Float16* __restrict__ xext, const _Float16* __restrict__ wXih,
            const float* __restrict__ bhh, const float* __restrict__ bfcp,
            const float* __restrict__ bhha, const float* __restrict__ bfca,
            const float* __restrict__ bm1,
            const float* __restrict__ Wm2, const float* __restrict__ bm2,
            float* __restrict__ out)
{
    __shared__ char smem[65536];   // COMB: Bw0|Bw1|Bf = 24K|24K|16K.  Acts: D.
    int b = blockIdx.x;
    const int tid = threadIdx.x;
    const int wv = tid >> 6, lane = tid & 63;
    const int quad = lane >> 4, l16 = lane & 15;

    // ===================== ACT1: pool + action GRU =====================
    if (b < A1B) {
        if (a1_t < 0) return;
        float* D = (float*)smem;
        const _Float16* proc = (a1_t & 1) ? proc1 : proc0;
        const _Float16* hain = (a1_t & 1) ? ha1 : ha0;
        _Float16*      haout = (a1_t & 1) ? ha0 : ha1;
        const int ra0 = b*16;

        // pool: feat = max_e proc (half8-vectorized)
        for (int i = tid; i < 16*32; i += 256) {
            int r = i >> 5, cg = (i & 31)*8;
            const _Float16* p = proc + ((size_t)(ra0 + r)*EE)*H + cg;
            half8 v = *(const half8*)p;
            float m[8];
            #pragma unroll
            for (int j = 0; j < 8; j++) m[j] = (float)v[j];
            #pragma unroll
            for (int e = 1; e < EE; e++) {
                half8 u = *(const half8*)(p + (size_t)e*H);
                #pragma unroll
                for (int j = 0; j < 8; j++) m[j] = fmaxf(m[j], (float)u[j]);
            }
            #pragma unroll
            for (int j = 0; j < 8; j++) D[r*DST + cg + j] = m[j];
        }
        __syncthreads();

        half8 Fh[8], Hh[8];
        #pragma unroll
        for (int kc = 0; kc < 8; kc++) {
            const float* fp = &D[l16*DST + quad*8 + kc*32];
            #pragma unroll
            for (int j = 0; j < 8; j++) Fh[kc][j] = (_Float16)fp[j];
            Hh[kc] = *(const half8*)(hain + (size_t)(ra0 + l16)*H + quad*8 + kc*32);
        }

        const int smp = ra0 + l16;
        const _Float16* gp = gia + (size_t)smp*G3;
        #pragma unroll
        for (int p = 0; p < 2; p++) {
            f32x4 gh[3][2], gx[3][2];
            #pragma unroll
            for (int g = 0; g < 3; g++)
                #pragma unroll
                for (int ch = 0; ch < 2; ch++) {
                    gh[g][ch] = (f32x4){0.f,0.f,0.f,0.f};
                    gx[g][ch] = (f32x4){0.f,0.f,0.f,0.f};
                }
            #pragma unroll
            for (int kc = 0; kc < 8; kc++)
                #pragma unroll
                for (int ch = 0; ch < 2; ch++)
                    #pragma unroll
                    for (int g = 0; g < 3; g++) {
                        const size_t cg = (size_t)(g*16 + wv*4 + p*2 + ch);
                        half8 bh = *(const half8*)(wWhha + (cg*8+kc)*512 + lane*8);
                        half8 bx = *(const half8*)(wWiha + (cg*8+kc)*512 + lane*8);
                        gh[g][ch] = MFMA16(bh, Hh[kc], gh[g][ch]);   // swapped
                        gx[g][ch] = MFMA16(bx, Fh[kc], gx[g][ch]);   // swapped
                    }
            #pragma unroll
            for (int ch = 0; ch < 2; ch++) {
                const int c0 = (wv*4 + p*2 + ch)*16 + quad*4;        // 4 consecutive cols
                half4 gr4 = *(const half4*)(gp + c0);
                half4 gz4 = *(const half4*)(gp + 256 + c0);
                half4 gn4 = *(const half4*)(gp + 512 + c0);
                f32x4 bn4 = *(const f32x4*)&bhha[512 + c0];
                half4 hp4 = *(const half4*)(hain + (size_t)smp*H + c0);
                half4 ho;
                #pragma unroll
                for (int r = 0; r < 4; r++) {
                    float rg = sigmoid_((float)gr4[r] + gx[0][ch][r] + gh[0][ch][r]);
                    float z  = sigmoid_((float)gz4[r] + gx[1][ch][r] + gh[1][ch][r]);
                    float n  = tanh_((float)gn4[r] + gx[2][ch][r] + rg*(gh[2][ch][r] + bn4[r]));
                    ho[r] = (_Float16)((1.f - z)*n + z*(float)hp4[r]);
                }
                *(half4*)(haout + (size_t)smp*H + c0) = ho;
            }
        }
        return;
    }
    b -= A1B;

    // ===================== ACT2: fc_a (col-split) =====================
    if (b < A2B) {
        if (a2_t < 0) return;
        const _Float16* hnew = (a2_t & 1) ? ha0 : ha1;   // ha[(t+1)&1]
        _Float16*       pca  = (a2_t & 1) ? pca1 : pca0;
        const int ra0 = (b >> 1)*16;
        const int half = b & 1;

        half8 Hh[8];
        #pragma unroll
        for (int kc = 0; kc < 8; kc++)
            Hh[kc] = *(const half8*)(hnew + (size_t)(ra0 + l16)*H + quad*8 + kc*32);

        f32x4 ac[2];
        ac[0] = (f32x4){0.f,0.f,0.f,0.f};
        ac[1] = (f32x4){0.f,0.f,0.f,0.f};
        #pragma unroll
        for (int kc = 0; kc < 8; kc++)
            #pragma unroll
            for (int ch = 0; ch < 2; ch++) {
                const size_t cidx = (size_t)(half*8 + wv*2 + ch);
                half8 w = *(const half8*)(wWfca + (cidx*8+kc)*512 + lane*8);
                ac[ch] = MFMA16(w, Hh[kc], ac[ch]);                  // swapped
            }
        const int smp = ra0 + l16;
        #pragma unroll
        for (int ch = 0; ch < 2; ch++) {
            const int c0 = (half*8 + wv*2 + ch)*16 + quad*4;
            f32x4 bs4 = *(const f32x4*)&bfca[c0];
            half4 po;
            #pragma unroll
            for (int r = 0; r < 4; r++)
                po[r] = (_Float16)elu_(ac[ch][r] + bs4[r]);
            *(half4*)(pca + (size_t)smp*H + c0) = po;
        }
        return;
    }
    b -= A2B;

    // ===================== ACT3: m1 + m2 =====================
    if (b < A3B) {
        if (a3_t < 0) return;
        float* D = (float*)smem;
        const _Float16* pca = (a3_t & 1) ? pca1 : pca0;
        const int ra0 = b*16;

        half8 Ph[8];
        #pragma unroll
        for (int kc = 0; kc < 8; kc++)
            Ph[kc] = *(const half8*)(pca + (size_t)(ra0 + l16)*H + quad*8 + kc*32);

        f32x4 ac[4];
        #pragma unroll
        for (int ch = 0; ch < 4; ch++) ac[ch] = (f32x4){0.f,0.f,0.f,0.f};
        #pragma unroll
        for (int kc = 0; kc < 8; kc++)
            #pragma unroll
            for (int ch = 0; ch < 4; ch++) {
                half8 w = *(const half8*)(wWm1 + ((size_t)(wv*4+ch)*8+kc)*512 + lane*8);
                ac[ch] = MFMA16(w, Ph[kc], ac[ch]);                  // swapped
            }
        #pragma unroll
        for (int ch = 0; ch < 4; ch++) {
            const int c0 = (wv*4 + ch)*16 + quad*4;
            f32x4 bs4 = *(const f32x4*)&bm1[c0];
            f32x4 dv;
            #pragma unroll
            for (int r = 0; r < 4; r++) dv[r] = elu_(ac[ch][r] + bs4[r]);
            *(f32x4*)&D[l16*DST + c0] = dv;
        }
        __syncthreads();

        if (tid < 32) {
            int r = tid >> 1, v = tid & 1;
            const float* w = Wm2 + (size_t)v*H;
            float s = bm2[v];
            #pragma unroll 4
            for (int i = 0; i < H/4; i++) {
                float4 a = *(const float4*)&D[r*DST + i*4];
                float4 c = *(const float4*)&w[i*4];
                s = fmaf(a.x,c.x,s); s = fmaf(a.y,c.y,s);
                s = fmaf(a.z,c.z,s); s = fmaf(a.w,c.w,s);
            }
            out[((size_t)a3_t*RA + ra0 + r)*NMV + v] = tanh_(s)*STEPSC;
        }
        return;
    }
    b -= A3B;

    // ==== COMBINED fc(fc_t)+gru(gru_t): single-barrier full-prefetch ====
    {
        const bool do_gru = (gru_t >= 0);
        const bool do_fc  = (fc_t >= 0);
        if (!do_gru && !do_fc) return;
        _Float16* Bw0 = (_Float16*)smem;            // gru slice 0 (24576 B)
        _Float16* Bw1 = (_Float16*)(smem + 24576);  // gru slice 1 (24576 B)
        _Float16* Bf  = (_Float16*)(smem + 49152);  // fc buffer   (16384 B)
        const int par = do_gru ? (gru_t & 1) : ((fc_t + 1) & 1);
        const _Float16* hin  = par ? hp1 : hp0;
        _Float16*       hout = par ? hp0 : hp1;            // gru output
        _Float16*       pout = (fc_t & 1) ? proc1 : proc0; // fc output
        const int xm = b % 160, ys = b / 160;              // ys in 0..7
        const int mt0 = xm*128 + wv*16;                    // tile 0 rows
        const int mt1 = mt0 + 64;                          // tile 1 rows

        // Stage ALL weight buffers at once (latency overlaps A-frag loads)
        if (do_gru) {
            #pragma unroll
            for (int k = 0; k < 6; k++) {
                int i = tid + 256*k;
                int g = i >> 9;
                cp16(wWhh + (size_t)(g*16 + ys*2)*4096 + (i & 511)*8, &Bw0[(size_t)i*8]);
            }
            #pragma unroll
            for (int k = 0; k < 6; k++) {
                int i = tid + 256*k;
                int g = i >> 9;
                cp16(wWhh + (size_t)(g*16 + ys*2+1)*4096 + (i & 511)*8, &Bw1[(size_t)i*8]);
            }
        }
        if (do_fc) {
            #pragma unroll
            for (int k = 0; k < 4; k++) {
                int i = tid + 256*k;
                cp16(wWfc + (size_t)ys*8192 + i*8, &Bf[(size_t)i*8]);
            }
        }

        // h fragments (B-operand), loaded ONCE, shared by gru slices AND fc
        half8 Ah[2][8];
        #pragma unroll
        for (int kc = 0; kc < 8; kc++) {
            Ah[0][kc] = *(const half8*)(hin + (size_t)(mt0 + l16)*H + quad*8 + kc*32);
            Ah[1][kc] = *(const half8*)(hin + (size_t)(mt1 + l16)*H + quad*8 + kc*32);
        }

        __syncthreads();               // ONE barrier: all staging landed

        if (do_gru) {
            half8 Xh[2];
            Xh[0] = *(const half8*)(xext + (size_t)(mt0 + l16)*32 + quad*8);
            Xh[1] = *(const half8*)(xext + (size_t)(mt1 + l16)*32 + quad*8);

            #pragma unroll
            for (int s = 0; s < 2; s++) {
                const int cs = ys*2 + s;                   // 0..15
                const _Float16* Bw = s ? Bw1 : Bw0;

                f32x4 acc[2][3], accHN[2];
                #pragma unroll
                for (int mt = 0; mt < 2; mt++) {
                    #pragma unroll
                    for (int g = 0; g < 3; g++) acc[mt][g] = (f32x4){0.f,0.f,0.f,0.f};
                    accHN[mt] = (f32x4){0.f,0.f,0.f,0.f};
                }
                #pragma unroll
                for (int kc = 0; kc < 8; kc++) {
                    #pragma unroll
                    for (int g = 0; g < 2; g++) {
                        half8 w = *(const half8*)&Bw[(g*8 + kc)*512 + lane*8];
                        acc[0][g] = MFMA16(w, Ah[0][kc], acc[0][g]); // swapped
                        acc[1][g] = MFMA16(w, Ah[1][kc], acc[1][g]);
                    }
                    half8 wn = *(const half8*)&Bw[(2*8 + kc)*512 + lane*8];
                    accHN[0] = MFMA16(wn, Ah[0][kc], accHN[0]);
                    accHN[1] = MFMA16(wn, Ah[1][kc], accHN[1]);
                }
                #pragma unroll
                for (int g = 0; g < 3; g++) {
                    half8 xw = *(const half8*)(wXih + (size_t)(g*16+cs)*512 + lane*8);
                    acc[0][g] = MFMA16(xw, Xh[0], acc[0][g]);        // swapped
                    acc[1][g] = MFMA16(xw, Xh[1], acc[1][g]);
                }

                const int c0 = cs*16 + quad*4;             // 4 consecutive cols
                f32x4 bn4 = *(const f32x4*)&bhh[512 + c0];
                #pragma unroll
                for (int mt = 0; mt < 2; mt++) {
                    const int smp = (mt ? mt1 : mt0) + l16;
                    half4 hp4 = *(const half4*)(hin + (size_t)smp*H + c0);
                    half4 ho;
                    #pragma unroll
                    for (int r = 0; r < 4; r++) {
                        float rg = sigmoid_(acc[mt][0][r]);
                        float z  = sigmoid_(acc[mt][1][r]);
                        float n  = tanh_(acc[mt][2][r] + rg*(accHN[mt][r] + bn4[r]));
                        ho[r] = (_Float16)((1.f - z)*n + z*(float)hp4[r]);
                    }
                    *(half4*)(hout + (size_t)smp*H + c0) = ho;
                }
            }
        }

        if (do_fc) {
            const int cs2 = ys;                            // 0..7, 32 cols
            f32x4 acc[2][2];
            #pragma unroll
            for (int mt = 0; mt < 2; mt++)
                #pragma unroll
                for (int ni = 0; ni < 2; ni++) acc[mt][ni] = (f32x4){0.f,0.f,0.f,0.f};
            #pragma unroll
            for (int kc = 0; kc < 8; kc++)
                #pragma unroll
                for (int ni = 0; ni < 2; ni++) {
                    half8 w = *(const half8*)&Bf[ni*4096 + kc*512 + lane*8];
                    acc[0][ni] = MFMA16(w, Ah[0][kc], acc[0][ni]);   // swapped
                    acc[1][ni] = MFMA16(w, Ah[1][kc], acc[1][ni]);
                }
            #pragma unroll
            for (int ni = 0; ni < 2; ni++) {
                const int c0 = cs2*32 + ni*16 + quad*4;
                f32x4 bs4 = *(const f32x4*)&bfcp[c0];
                #pragma unroll
                for (int mt = 0; mt < 2; mt++) {
                    const int smp = (mt ? mt1 : mt0) + l16;
                    half4 po;
                    #pragma unroll
                    for (int r = 0; r < 4; r++)
                        po[r] = (_Float16)elu_(acc[mt][ni][r] + bs4[r]);
                    *(half4*)(pout + (size_t)smp*H + c0) = po;
                }
            }
        }
    }
}

extern "C" void kernel_launch(void* const* d_in, const int* in_sizes, int n_in,
                              void* d_out, int out_size, void* d_ws, size_t ws_size,
                              hipStream_t stream)
{
    const float* obs  = (const float*)d_in[0];
    const float* phys = (const float*)d_in[1];
    const float* goals= (const float*)d_in[2];
    const float* memp = (const float*)d_in[3];
    const float* mema = (const float*)d_in[4];
    const float* Wihp = (const float*)d_in[5];
    const float* Whhp = (const float*)d_in[6];
    const float* bihp = (const float*)d_in[7];
    const float* bhhp = (const float*)d_in[8];
    const float* Wfcp = (const float*)d_in[9];
    const float* bfcp = (const float*)d_in[10];
    const float* Wiha = (const float*)d_in[11];
    const float* Whha = (const float*)d_in[12];
    const float* biha = (const float*)d_in[13];
    const float* bhha = (const float*)d_in[14];
    const float* Wfca = (const float*)d_in[15];
    const float* bfca = (const float*)d_in[16];
    const float* Wm1  = (const float*)d_in[17];
    const float* bm1  = (const float*)d_in[18];
    const float* Wm2  = (const float*)d_in[19];
    const float* bm2  = (const float*)d_in[20];
    float* out = (float*)d_out;
    (void)ws_size;

    char* base = (char*)d_ws;
    size_t off = 0;
    auto alloc = [&](size_t bytes) -> char* {
        char* p = base + off;
        off += (bytes + 255) & ~(size_t)255;
        return p;
    };
    _Float16* wp_whh = (_Float16*)alloc((size_t)G3*H*2);
    _Float16* wp_wfc = (_Float16*)alloc((size_t)H*H*2);
    _Float16* wa_whh = (_Float16*)alloc((size_t)G3*H*2);
    _Float16* wa_wih = (_Float16*)alloc((size_t)G3*H*2);
    _Float16* wa_wfc = (_Float16*)alloc((size_t)H*H*2);
    _Float16* wa_wm1 = (_Float16*)alloc((size_t)H*H*2);
    _Float16* gia    = (_Float16*)alloc((size_t)RA*G3*2);
    _Float16* hp0    = (_Float16*)alloc((size_t)RP*H*2);
    _Float16* hp1    = (_Float16*)alloc((size_t)RP*H*2);
    _Float16* proc0  = (_Float16*)alloc((size_t)RP*H*2);
    _Float16* proc1  = (_Float16*)alloc((size_t)RP*H*2);
    _Float16* ha0    = (_Float16*)alloc((size_t)RA*H*2);
    _Float16* ha1    = (_Float16*)alloc((size_t)RA*H*2);
    _Float16* pca0   = (_Float16*)alloc((size_t)RA*H*2);
    _Float16* pca1   = (_Float16*)alloc((size_t)RA*H*2);
    _Float16* xext   = (_Float16*)alloc((size_t)RP*32*2);   // 1.25 MB
    _Float16* wxih   = (_Float16*)alloc((size_t)48*512*2);  // 48 KB

    // --- pre-pass ---
    k_splitw<<<(G3*H+255)/256, 256, 0, stream>>>(Whhp, wp_whh, G3*H, H);
    k_splitw<<<(H*H+255)/256, 256, 0, stream>>>(Wfcp, wp_wfc, H*H, H);
    k_splitw<<<(G3*H+255)/256, 256, 0, stream>>>(Whha, wa_whh, G3*H, H);
    k_splitw<<<(G3*H+255)/256, 256, 0, stream>>>(Wiha, wa_wih, G3*H, 259);
    k_splitw<<<(H*H+255)/256, 256, 0, stream>>>(Wfca, wa_wfc, H*H, H);
    k_splitw<<<(H*H+255)/256, 256, 0, stream>>>(Wm1,  wa_wm1, H*H, H);
    k_gia_goal<<<RA*G3/256, 256, 0, stream>>>(goals, Wiha, biha, bhha, gia);
    k_cvt<<<((size_t)RP*H+255)/256, 256, 0, stream>>>(memp, hp0, RP*H);
    k_cvt<<<((size_t)RA*H+255)/256, 256, 0, stream>>>(mema, ha0, RA*H);
    k_xext<<<RP*32/256, 256, 0, stream>>>(obs, phys, xext);
    k_wxih<<<48*512/256, 256, 0, stream>>>(Wihp, bihp, bhhp, wxih);

    // --- 14 pipelined launches: L = {gru(L), fc(L-1), act1(L-2), act2(L-3), act3(L-4)} ---
    const int NB = A1B + A2B + A3B + COMB;
    for (int L = 0; L <= TT + 3; L++) {
        int gru_t = (L <= TT-1) ? L : -1;
        int fc_t  = (L-1 >= 0 && L-1 <= TT-1) ? L-1 : -1;
        int a1_t  = (L-2 >= 0 && L-2 <= TT-1) ? L-2 : -1;
        int a2_t  = (L-3 >= 0 && L-3 <= TT-1) ? L-3 : -1;
        int a3_t  = (L-4 >= 0 && L-4 <= TT-1) ? L-4 : -1;
        k_step<<<NB, 256, 0, stream>>>(gru_t, fc_t, a1_t, a2_t, a3_t,
                                       hp0, hp1, proc0, proc1, ha0, ha1, pca0, pca1,
                                       wp_whh, wp_wfc, wa_whh, wa_wih, wa_wfc, wa_wm1,
                                       gia, xext, wxih,
                                       bhhp, bfcp,
                                       bhha, bfca, bm1, Wm2, bm2, out);
    }
}